// Round 7
// baseline (352.363 us; speedup 1.0000x reference)
//
#include <hip/hip_runtime.h>
#include <hip/hip_bf16.h>
#include <cstdint>
#include <cstddef>

// ---------------- types / helpers ----------------
typedef float  f32x4  __attribute__((ext_vector_type(4)));
typedef __bf16 bf16x8 __attribute__((ext_vector_type(8)));
typedef unsigned short u16x8 __attribute__((ext_vector_type(8)));

__device__ __forceinline__ unsigned short f2bf(float f) {
    unsigned u = __float_as_uint(f);
    u += 0x7FFFu + ((u >> 16) & 1u);   // round-to-nearest-even
    return (unsigned short)(u >> 16);
}

// ---------------- problem constants ----------------
// B=64, C=80, IN_CH=300, J=8192, S=8, OUT=1024
// feature [64,2048,14,14] (131072 rows of 196), out [64,80]

// ---------------- ws layout (bytes) ----------------
constexpr size_t OFF_FEATB = 0;          // 64*2048 bf16  = 262144
constexpr size_t OFF_X2B   = 262144;     // 80*1024 bf16  = 163840
constexpr size_t OFF_WG2T  = 425984;     // 2048*1024 f32 = 8388608
constexpr size_t OFF_XB    = 8814592;    // 80*2048 bf16  = 327680
constexpr size_t OFF_IMG   = 9142272;    // 64*8192 f32   = 2097152
constexpr size_t OFF_CLS   = 11239424;   // 80*8192 f32   = 2621440
constexpr size_t OFF_G     = 13860864;   // 80*8192 f32   = 2621440

// =================== D1 roles (256 threads) ===================

// maxpool: 16 lanes per row, 4 rows per wave, 64 rows per vbid.
__device__ __forceinline__ void maxpool_role(int vbid, const float* __restrict__ feature,
                                             unsigned short* __restrict__ featb) {
    int wave = threadIdx.x >> 6, lane = threadIdx.x & 63;
    int r = lane >> 4, q = lane & 15;
    #pragma unroll
    for (int it = 0; it < 4; ++it) {              // 4 waves x 4 rows x 4 it = 64 rows
        int rr = vbid * 64 + it * 16 + wave * 4 + r;
        const float4* p = (const float4*)(feature + (size_t)rr * 196);
        float4 a = p[q], b = p[q + 16], c = p[q + 32];
        float m = fmaxf(fmaxf(fmaxf(a.x, a.y), fmaxf(a.z, a.w)),
                 fmaxf(fmaxf(fmaxf(b.x, b.y), fmaxf(b.z, b.w)),
                       fmaxf(fmaxf(c.x, c.y), fmaxf(c.z, c.w))));
        if (q == 0) {                             // tail float4 (192..195)
            float4 d = p[48];
            m = fmaxf(m, fmaxf(fmaxf(d.x, d.y), fmaxf(d.z, d.w)));
        }
        #pragma unroll
        for (int off = 1; off < 16; off <<= 1) m = fmaxf(m, __shfl_xor(m, off));
        if (q == 0) featb[rr] = f2bf(m);
    }
}

// transpose W_gc2 [1024][2048] -> wg2t [2048][1024], one 64x64 tile per block.
__device__ __forceinline__ void transpose_role(int idx, const float* __restrict__ in,
                                               float* __restrict__ out, float* t /*64*65*/) {
    int c0 = (idx & 31) * 64, r0 = (idx >> 5) * 64;
    int tx = threadIdx.x & 63, ty = threadIdx.x >> 6;   // 64 x 4
    #pragma unroll
    for (int i = 0; i < 64; i += 4)
        t[(i + ty) * 65 + tx] = in[(size_t)(r0 + i + ty) * 2048 + c0 + tx];
    __syncthreads();
    #pragma unroll
    for (int i = 0; i < 64; i += 4)
        out[(size_t)(c0 + i + ty) * 1024 + r0 + tx] = t[tx * 65 + i + ty];
}

// fully-fused GCN front: block owns 16 columns (j0=idx*16); computes y0, x1, x2
// for its slice entirely in LDS. 256 thr: j = t&15, kb = t>>4 (16 rows x 5 it).
__device__ __forceinline__ void gcn_fused_role(int idx, const float* __restrict__ inp,
                                               const float* __restrict__ W1,
                                               const float* __restrict__ A,
                                               unsigned short* __restrict__ x2b,
                                               float* smem) {
    float* adjs = smem;           // [80][80]  25.6 KB
    float* y0s  = smem + 6400;    // [80][16]
    float* x1s  = smem + 7680;    // [80][16]
    float* dinv = smem + 8960;    // [80]
    int t = threadIdx.x;
    int j0 = idx * 16;
    int j = t & 15, kb = t >> 4;                  // kb 0..15

    if (t < 80) {
        const float4* ar = (const float4*)(A + t * 80);
        float4 s4 = {0.f, 0.f, 0.f, 0.f};
        #pragma unroll
        for (int q = 0; q < 20; q++) {
            float4 v = ar[q];
            s4.x += v.x; s4.y += v.y; s4.z += v.z; s4.w += v.w;
        }
        dinv[t] = 1.0f / sqrtf(s4.x + s4.y + s4.z + s4.w);
    }
    __syncthreads();
    for (int i = t; i < 6400; i += 256) {
        int r = i / 80, cc = i % 80;
        adjs[i] = A[cc * 80 + r] * dinv[r] * dinv[cc];
    }

    // y0[k, j0+j] = sum_e inp[k,e] * W1[e, j0+j],  k = it*16 + kb
    float accs[5];
    #pragma unroll
    for (int it = 0; it < 5; ++it) {
        int k = it * 16 + kb;
        const float* ir = inp + k * 300;
        const float* wc = W1 + j0 + j;
        float acc = 0.f;
        #pragma unroll 4
        for (int e = 0; e < 300; e++) acc = fmaf(ir[e], wc[(size_t)e * 1024], acc);
        accs[it] = acc;
    }
    __syncthreads();                               // adjs complete
    #pragma unroll
    for (int it = 0; it < 5; ++it) y0s[(it * 16 + kb) * 16 + j] = accs[it];
    __syncthreads();                               // y0s visible

    #pragma unroll
    for (int it = 0; it < 5; ++it) {
        int c = it * 16 + kb;
        float acc = 0.f;
        #pragma unroll 4
        for (int k = 0; k < 80; k++) acc = fmaf(adjs[c * 80 + k], y0s[k * 16 + j], acc);
        if (acc < 0.f) acc *= 0.2f;
        x1s[c * 16 + j] = acc;
    }
    __syncthreads();                               // x1s visible

    #pragma unroll
    for (int it = 0; it < 5; ++it) {
        int c = it * 16 + kb;
        float acc = 0.f;
        #pragma unroll 4
        for (int k = 0; k < 80; k++) acc = fmaf(adjs[c * 80 + k], x1s[k * 16 + j], acc);
        x2b[c * 1024 + j0 + j] = f2bf(acc);
    }
}

// =================== MFMA GEMM (256 thr, BN=16, in-block 4-way K-split) ===================
// out[m,n] = sum_k X[m,k]*W[n,k] (+bias[n]); X bf16 [MF*16][K], W f32 [N][K].
template <int MF>
__device__ __forceinline__ void gemm_block(int bx, const unsigned short* __restrict__ X,
                                           const float* __restrict__ W,
                                           const float* __restrict__ bias,
                                           float* __restrict__ outf,
                                           unsigned short* __restrict__ outb,
                                           int N, int K, float (*red)[64][21]) {
    int tid = threadIdx.x;
    int ks = tid >> 6, lane = tid & 63;           // wave = k-split
    int n = bx * 16 + (lane & 15);
    int rowa = lane & 15;
    int koff = (lane >> 4) * 8;
    int Kc = K >> 2;
    int k0 = ks * Kc;

    f32x4 acc[MF];
    #pragma unroll
    for (int i = 0; i < MF; i++) acc[i] = (f32x4)(0.f);

    const float* wrow = W + (size_t)n * K;

    #pragma unroll 2
    for (int k = k0; k < k0 + Kc; k += 32) {
        float4 w0 = *(const float4*)(wrow + k + koff);
        float4 w1 = *(const float4*)(wrow + k + koff + 4);
        u16x8 bu;
        bu[0] = f2bf(w0.x); bu[1] = f2bf(w0.y); bu[2] = f2bf(w0.z); bu[3] = f2bf(w0.w);
        bu[4] = f2bf(w1.x); bu[5] = f2bf(w1.y); bu[6] = f2bf(w1.z); bu[7] = f2bf(w1.w);
        bf16x8 bf = __builtin_bit_cast(bf16x8, bu);
        #pragma unroll
        for (int mf = 0; mf < MF; mf++) {
            u16x8 au = *(const u16x8*)(X + (size_t)(mf * 16 + rowa) * K + k + koff);
            acc[mf] = __builtin_amdgcn_mfma_f32_16x16x32_bf16(
                __builtin_bit_cast(bf16x8, au), bf, acc[mf], 0, 0, 0);
        }
    }

    #pragma unroll
    for (int mf = 0; mf < MF; mf++)
        #pragma unroll
        for (int i = 0; i < 4; i++)
            red[ks][lane][mf * 4 + i] = acc[mf][i];
    __syncthreads();

    // reduce 4 k-splits (same order as before: ks 0+1+2+3) + bias + write
    int lane2 = tid & 63, sg = tid >> 6;
    int n2 = bx * 16 + (lane2 & 15);
    float b = bias ? bias[n2] : 0.f;
    #pragma unroll
    for (int mf = 0; mf < MF; mf++) {
        int slot = mf * 4 + sg;
        float s = red[0][lane2][slot] + red[1][lane2][slot]
                + red[2][lane2][slot] + red[3][lane2][slot] + b;
        int row = mf * 16 + (lane2 >> 4) * 4 + sg;
        size_t o = (size_t)row * N + n2;
        if (outf) outf[o] = s;
        if (outb) outb[o] = f2bf(s);
    }
}

// =================== kernels (5 dispatches) ===================

// D1: gcn(0-63) | transpose(64-575) | maxpool(576-2623)
__global__ __launch_bounds__(256, 4) void kD1(const float* __restrict__ feature,
                                              unsigned short* __restrict__ featb,
                                              const float* __restrict__ inp,
                                              const float* __restrict__ W1,
                                              const float* __restrict__ A,
                                              unsigned short* __restrict__ x2b,
                                              const float* __restrict__ Wg2,
                                              float* __restrict__ wg2t) {
    __shared__ __align__(16) float smem[9040];    // 36.2 KB union
    int b = blockIdx.x;
    if (b < 64)       gcn_fused_role(b, inp, W1, A, x2b, smem);
    else if (b < 576) transpose_role(b - 64, Wg2, wg2t, smem);
    else              maxpool_role(b - 576, feature, featb);
}

// D2: img units (0-511) | xb units (512-639)
__global__ __launch_bounds__(256, 4) void kD2(const unsigned short* __restrict__ featb,
                                              const float* __restrict__ W_img,
                                              const float* __restrict__ b_img,
                                              float* __restrict__ img,
                                              const unsigned short* __restrict__ x2b,
                                              const float* __restrict__ wg2t,
                                              unsigned short* __restrict__ xb) {
    __shared__ __align__(16) float red[4][64][21];   // 21.5 KB
    int b = blockIdx.x;
    if (b < 512) gemm_block<4>(b, featb, W_img, b_img, img, nullptr, 8192, 2048, red);
    else         gemm_block<5>(b - 512, x2b, wg2t, nullptr, nullptr, xb, 2048, 1024, red);
}

// D3: cls = xb @ W_cls^T + b_cls (512 blocks)
__global__ __launch_bounds__(256, 4) void kD3(const unsigned short* __restrict__ xb,
                                              const float* __restrict__ W_cls,
                                              const float* __restrict__ b_cls,
                                              float* __restrict__ cls) {
    __shared__ __align__(16) float red[4][64][21];
    gemm_block<5>(blockIdx.x, xb, W_cls, b_cls, cls, nullptr, 8192, 2048, red);
}

// D4: G[c2,j] = sum_c cls[c,j] * W_ml[c2, c*1024 + (j>>3)]; 640 units (64 o x 10 c2)
__global__ __launch_bounds__(256, 4) void kD4(const float* __restrict__ cls,
                                              const float* __restrict__ W_ml,
                                              float* __restrict__ G) {
    __shared__ __align__(16) float smem[8 * 80 * 16];   // 40 KB
    float (*wml)[80][16] = (float (*)[80][16])smem;
    int idx = blockIdx.x;
    int o0  = (idx & 63) * 16;
    int c2b = (idx >> 6) * 8;
    int j0  = o0 * 8;
    for (int i = threadIdx.x; i < 8 * 80 * 16; i += 256) {
        int ol = i & 15, c = (i >> 4) % 80, c2 = i / 1280;
        wml[c2][c][ol] = W_ml[(size_t)(c2b + c2) * 81920 + c * 1024 + o0 + ol];
    }
    __syncthreads();
    int jl  = threadIdx.x & 127;
    int c2h = (threadIdx.x >> 7) * 4;
    int ol  = jl >> 3;
    float acc[4] = {0.f, 0.f, 0.f, 0.f};
    for (int c = 0; c < 80; c++) {
        float cv = cls[(size_t)c * 8192 + j0 + jl];
        #pragma unroll
        for (int i = 0; i < 4; i++) acc[i] = fmaf(cv, wml[c2h + i][c][ol], acc[i]);
    }
    #pragma unroll
    for (int i = 0; i < 4; i++) G[(size_t)(c2b + c2h + i) * 8192 + j0 + jl] = acc[i];
}

// D5: out[b,c2] = sum_j img[b,j]*G[c2,j] + b_ml[c2]; 160 blocks (16 btile x 10 cg)
__global__ __launch_bounds__(256, 4) void kD5(const float* __restrict__ img,
                                              const float* __restrict__ G,
                                              const float* __restrict__ b_ml,
                                              float* __restrict__ out) {
    __shared__ float sm[4][32];
    int btile = blockIdx.x & 15, cg = blockIdx.x >> 4;
    int kc = threadIdx.x >> 6, lane = threadIdx.x & 63;
    float acc[4][8];
    #pragma unroll
    for (int q = 0; q < 4; q++)
        #pragma unroll
        for (int i = 0; i < 8; i++) acc[q][i] = 0.f;

    #pragma unroll
    for (int step = 0; step < 8; step++) {
        int k = kc * 2048 + step * 256 + lane * 4;
        float4 gv[8];
        #pragma unroll
        for (int i = 0; i < 8; i++) gv[i] = *(const float4*)(G + (size_t)(cg * 8 + i) * 8192 + k);
        #pragma unroll
        for (int q = 0; q < 4; q++) {
            float4 iv = *(const float4*)(img + (size_t)(btile * 4 + q) * 8192 + k);
            #pragma unroll
            for (int i = 0; i < 8; i++) {
                acc[q][i] = fmaf(iv.x, gv[i].x, acc[q][i]);
                acc[q][i] = fmaf(iv.y, gv[i].y, acc[q][i]);
                acc[q][i] = fmaf(iv.z, gv[i].z, acc[q][i]);
                acc[q][i] = fmaf(iv.w, gv[i].w, acc[q][i]);
            }
        }
    }
    #pragma unroll
    for (int q = 0; q < 4; q++)
        #pragma unroll
        for (int i = 0; i < 8; i++) {
            float v = acc[q][i];
            #pragma unroll
            for (int off = 32; off; off >>= 1) v += __shfl_xor(v, off);
            if (lane == 0) sm[kc][q * 8 + i] = v;
        }
    __syncthreads();
    if (threadIdx.x < 32) {
        int i = threadIdx.x & 7;
        float s = b_ml[cg * 8 + i];
        #pragma unroll
        for (int kk = 0; kk < 4; kk++) s += sm[kk][threadIdx.x];
        int q = threadIdx.x >> 3;
        out[(size_t)(btile * 4 + q) * 80 + cg * 8 + i] = s;
    }
}

// ---------------- launch ----------------
extern "C" void kernel_launch(void* const* d_in, const int* in_sizes, int n_in,
                              void* d_out, int out_size, void* d_ws, size_t ws_size,
                              hipStream_t stream) {
    (void)in_sizes; (void)n_in; (void)out_size; (void)ws_size;
    const float* feature = (const float*)d_in[0];
    const float* inp     = (const float*)d_in[1];
    const float* A       = (const float*)d_in[2];
    const float* W_gc1   = (const float*)d_in[3];
    const float* W_gc2   = (const float*)d_in[4];
    const float* W_img   = (const float*)d_in[5];
    const float* b_img   = (const float*)d_in[6];
    const float* W_cls   = (const float*)d_in[7];
    const float* b_cls   = (const float*)d_in[8];
    const float* W_ml    = (const float*)d_in[9];
    const float* b_ml    = (const float*)d_in[10];
    float* out = (float*)d_out;
    char*  ws  = (char*)d_ws;

    unsigned short* featb = (unsigned short*)(ws + OFF_FEATB);
    unsigned short* x2b   = (unsigned short*)(ws + OFF_X2B);
    float* wg2t = (float*)(ws + OFF_WG2T);
    unsigned short* xb    = (unsigned short*)(ws + OFF_XB);
    float* img  = (float*)(ws + OFF_IMG);
    float* cls  = (float*)(ws + OFF_CLS);
    float* G    = (float*)(ws + OFF_G);

    kD1<<<2624, 256, 0, stream>>>(feature, featb, inp, W_gc1, A, x2b, W_gc2, wg2t);
    kD2<<<640,  256, 0, stream>>>(featb, W_img, b_img, img, x2b, wg2t, xb);
    kD3<<<512,  256, 0, stream>>>(xb, W_cls, b_cls, cls);
    kD4<<<640,  256, 0, stream>>>(cls, W_ml, G);
    kD5<<<160,  256, 0, stream>>>(img, G, b_ml, out);
}

// Round 8
// 271.615 us; speedup vs baseline: 1.2973x; 1.2973x over previous
//
#include <hip/hip_runtime.h>
#include <hip/hip_bf16.h>
#include <cstdint>
#include <cstddef>

// ---------------- types / helpers ----------------
typedef float  f32x4  __attribute__((ext_vector_type(4)));
typedef __bf16 bf16x8 __attribute__((ext_vector_type(8)));
typedef unsigned short u16x8 __attribute__((ext_vector_type(8)));

__device__ __forceinline__ unsigned short f2bf(float f) {
    unsigned u = __float_as_uint(f);
    u += 0x7FFFu + ((u >> 16) & 1u);   // round-to-nearest-even
    return (unsigned short)(u >> 16);
}

// ---------------- problem constants ----------------
// B=64, C=80, IN_CH=300, J=8192, S=8, OUT=1024
// feature [64,2048,14,14] (131072 rows of 196), out [64,80]

// ---------------- ws layout (bytes) ----------------
constexpr size_t OFF_FEATB = 0;          // 64*2048 bf16  = 262144
constexpr size_t OFF_X2B   = 262144;     // 80*1024 bf16  = 163840
constexpr size_t OFF_XB    = 425984;     // 80*2048 bf16  = 327680
constexpr size_t OFF_IMG   = 753664;     // 64*8192 f32   = 2097152
constexpr size_t OFF_CLS   = 2850816;    // 80*8192 f32   = 2621440
constexpr size_t OFF_G     = 5472256;    // 80*8192 f32   = 2621440

// =================== D1 roles (256 threads) ===================

// maxpool: 16 lanes per row, 4 rows per wave, 64 rows per vbid.
__device__ __forceinline__ void maxpool_role(int vbid, const float* __restrict__ feature,
                                             unsigned short* __restrict__ featb) {
    int wave = threadIdx.x >> 6, lane = threadIdx.x & 63;
    int r = lane >> 4, q = lane & 15;
    #pragma unroll
    for (int it = 0; it < 4; ++it) {              // 4 waves x 4 rows x 4 it = 64 rows
        int rr = vbid * 64 + it * 16 + wave * 4 + r;
        const float4* p = (const float4*)(feature + (size_t)rr * 196);
        float4 a = p[q], b = p[q + 16], c = p[q + 32];
        float m = fmaxf(fmaxf(fmaxf(a.x, a.y), fmaxf(a.z, a.w)),
                 fmaxf(fmaxf(fmaxf(b.x, b.y), fmaxf(b.z, b.w)),
                       fmaxf(fmaxf(c.x, c.y), fmaxf(c.z, c.w))));
        if (q == 0) {                             // tail float4 (192..195)
            float4 d = p[48];
            m = fmaxf(m, fmaxf(fmaxf(d.x, d.y), fmaxf(d.z, d.w)));
        }
        #pragma unroll
        for (int off = 1; off < 16; off <<= 1) m = fmaxf(m, __shfl_xor(m, off));
        if (q == 0) featb[rr] = f2bf(m);
    }
}

// GCN front: block owns 8 j-columns (j0 = idx*8). Thread (j = t&7, slot = t>>3)
// computes y0/x1/x2 for c = {slot, slot+32, slot+64(<80)}. W1 column value is
// loaded ONCE per k and reused across the 3 c-accumulators (register reuse).
// 128 blocks x 32 slots -> every (c,j) exactly once. All f32; x2 -> bf16.
__device__ __forceinline__ void gcn_front_role(int idx, const float* __restrict__ inp,
                                               const float* __restrict__ W1,
                                               const float* __restrict__ A,
                                               unsigned short* __restrict__ x2b,
                                               float* smem) {
    float* adjs = smem;            // [80][80] 25600 f
    float* y0s  = smem + 6400;     // [80][8]
    float* x1s  = smem + 7040;     // [80][8]
    float* dinv = smem + 7680;     // [80]
    int t = threadIdx.x;
    int j = t & 7, slot = t >> 3;                 // slot 0..31
    int j0 = idx * 8;
    int c0 = slot, c1 = slot + 32, c2 = slot + 64;
    bool has3 = (slot < 16);                      // wave-uniform (slots 0-15 = waves 0,1)

    if (t < 80) {
        const float4* ar = (const float4*)(A + t * 80);
        float4 s4 = {0.f, 0.f, 0.f, 0.f};
        #pragma unroll
        for (int q = 0; q < 20; q++) {
            float4 v = ar[q];
            s4.x += v.x; s4.y += v.y; s4.z += v.z; s4.w += v.w;
        }
        dinv[t] = 1.0f / sqrtf(s4.x + s4.y + s4.z + s4.w);
    }
    __syncthreads();
    for (int i = t; i < 6400; i += 256) {
        int r = i / 80, cc = i % 80;
        adjs[i] = A[cc * 80 + r] * dinv[r] * dinv[cc];
    }

    // y0: 300 serial k, 4 independent loads per k (W1 col + 3 inp rows)
    const float* wcol = W1 + j0 + j;
    const float* i0 = inp + c0 * 300;
    const float* i1 = inp + c1 * 300;
    const float* i2 = inp + c2 * 300;
    float a0 = 0.f, a1 = 0.f, a2 = 0.f;
    #pragma unroll 4
    for (int k = 0; k < 300; k++) {
        float w = wcol[(size_t)k * 1024];
        a0 = fmaf(i0[k], w, a0);
        a1 = fmaf(i1[k], w, a1);
        if (has3) a2 = fmaf(i2[k], w, a2);
    }
    __syncthreads();                               // adjs fill complete
    y0s[c0 * 8 + j] = a0;
    y0s[c1 * 8 + j] = a1;
    if (has3) y0s[c2 * 8 + j] = a2;
    __syncthreads();                               // y0s visible

    // x1 = leaky(adj @ y0) for this block's j-slice
    float b0 = 0.f, b1 = 0.f, b2 = 0.f;
    #pragma unroll 4
    for (int e = 0; e < 80; e++) {
        float y = y0s[e * 8 + j];
        b0 = fmaf(adjs[c0 * 80 + e], y, b0);
        b1 = fmaf(adjs[c1 * 80 + e], y, b1);
        if (has3) b2 = fmaf(adjs[c2 * 80 + e], y, b2);
    }
    if (b0 < 0.f) b0 *= 0.2f;
    if (b1 < 0.f) b1 *= 0.2f;
    if (b2 < 0.f) b2 *= 0.2f;
    x1s[c0 * 8 + j] = b0;
    x1s[c1 * 8 + j] = b1;
    if (has3) x1s[c2 * 8 + j] = b2;
    __syncthreads();                               // x1s visible

    // x2 = adj @ x1 -> bf16 global
    float d0 = 0.f, d1 = 0.f, d2 = 0.f;
    #pragma unroll 4
    for (int e = 0; e < 80; e++) {
        float x = x1s[e * 8 + j];
        d0 = fmaf(adjs[c0 * 80 + e], x, d0);
        d1 = fmaf(adjs[c1 * 80 + e], x, d1);
        if (has3) d2 = fmaf(adjs[c2 * 80 + e], x, d2);
    }
    x2b[c0 * 1024 + j0 + j] = f2bf(d0);
    x2b[c1 * 1024 + j0 + j] = f2bf(d1);
    if (has3) x2b[c2 * 1024 + j0 + j] = f2bf(d2);
}

// =================== MFMA GEMMs (256 thr, BN=16, in-block 4-way K-split) ===================
// W in [N][K] row-major (K-contiguous): fast float4 loads.
template <int MF>
__device__ __forceinline__ void gemm_block(int bx, const unsigned short* __restrict__ X,
                                           const float* __restrict__ W,
                                           const float* __restrict__ bias,
                                           float* __restrict__ outf,
                                           unsigned short* __restrict__ outb,
                                           int N, int K, float (*red)[64][21]) {
    int tid = threadIdx.x;
    int ks = tid >> 6, lane = tid & 63;           // wave = k-split
    int n = bx * 16 + (lane & 15);
    int rowa = lane & 15;
    int koff = (lane >> 4) * 8;
    int Kc = K >> 2;
    int k0 = ks * Kc;

    f32x4 acc[MF];
    #pragma unroll
    for (int i = 0; i < MF; i++) acc[i] = (f32x4)(0.f);

    const float* wrow = W + (size_t)n * K;

    #pragma unroll 2
    for (int k = k0; k < k0 + Kc; k += 32) {
        float4 w0 = *(const float4*)(wrow + k + koff);
        float4 w1 = *(const float4*)(wrow + k + koff + 4);
        u16x8 bu;
        bu[0] = f2bf(w0.x); bu[1] = f2bf(w0.y); bu[2] = f2bf(w0.z); bu[3] = f2bf(w0.w);
        bu[4] = f2bf(w1.x); bu[5] = f2bf(w1.y); bu[6] = f2bf(w1.z); bu[7] = f2bf(w1.w);
        bf16x8 bf = __builtin_bit_cast(bf16x8, bu);
        #pragma unroll
        for (int mf = 0; mf < MF; mf++) {
            u16x8 au = *(const u16x8*)(X + (size_t)(mf * 16 + rowa) * K + k + koff);
            acc[mf] = __builtin_amdgcn_mfma_f32_16x16x32_bf16(
                __builtin_bit_cast(bf16x8, au), bf, acc[mf], 0, 0, 0);
        }
    }

    #pragma unroll
    for (int mf = 0; mf < MF; mf++)
        #pragma unroll
        for (int i = 0; i < 4; i++)
            red[ks][lane][mf * 4 + i] = acc[mf][i];
    __syncthreads();

    int lane2 = tid & 63, sg = tid >> 6;
    int n2 = bx * 16 + (lane2 & 15);
    float b = bias ? bias[n2] : 0.f;
    #pragma unroll
    for (int mf = 0; mf < MF; mf++) {
        int slot = mf * 4 + sg;
        float s = red[0][lane2][slot] + red[1][lane2][slot]
                + red[2][lane2][slot] + red[3][lane2][slot] + b;
        int row = mf * 16 + (lane2 >> 4) * 4 + sg;
        size_t o = (size_t)row * N + n2;
        if (outf) outf[o] = s;
        if (outb) outb[o] = f2bf(s);
    }
}

// W in [K][N] row-major (N-contiguous): strided B loads — no transpose needed.
template <int MF>
__device__ __forceinline__ void gemm_block_kn(int bx, const unsigned short* __restrict__ X,
                                              const float* __restrict__ Wkn,
                                              const float* __restrict__ bias,
                                              float* __restrict__ outf,
                                              unsigned short* __restrict__ outb,
                                              int N, int K, float (*red)[64][21]) {
    int tid = threadIdx.x;
    int ks = tid >> 6, lane = tid & 63;
    int n = bx * 16 + (lane & 15);
    int rowa = lane & 15;
    int koff = (lane >> 4) * 8;
    int Kc = K >> 2;
    int k0 = ks * Kc;

    f32x4 acc[MF];
    #pragma unroll
    for (int i = 0; i < MF; i++) acc[i] = (f32x4)(0.f);

    #pragma unroll 2
    for (int k = k0; k < k0 + Kc; k += 32) {
        float w[8];
        #pragma unroll
        for (int i = 0; i < 8; i++) w[i] = Wkn[(size_t)(k + koff + i) * N + n];
        u16x8 bu;
        #pragma unroll
        for (int i = 0; i < 8; i++) bu[i] = f2bf(w[i]);
        bf16x8 bf = __builtin_bit_cast(bf16x8, bu);
        #pragma unroll
        for (int mf = 0; mf < MF; mf++) {
            u16x8 au = *(const u16x8*)(X + (size_t)(mf * 16 + rowa) * K + k + koff);
            acc[mf] = __builtin_amdgcn_mfma_f32_16x16x32_bf16(
                __builtin_bit_cast(bf16x8, au), bf, acc[mf], 0, 0, 0);
        }
    }

    #pragma unroll
    for (int mf = 0; mf < MF; mf++)
        #pragma unroll
        for (int i = 0; i < 4; i++)
            red[ks][lane][mf * 4 + i] = acc[mf][i];
    __syncthreads();

    int lane2 = tid & 63, sg = tid >> 6;
    int n2 = bx * 16 + (lane2 & 15);
    float b = bias ? bias[n2] : 0.f;
    #pragma unroll
    for (int mf = 0; mf < MF; mf++) {
        int slot = mf * 4 + sg;
        float s = red[0][lane2][slot] + red[1][lane2][slot]
                + red[2][lane2][slot] + red[3][lane2][slot] + b;
        int row = mf * 16 + (lane2 >> 4) * 4 + sg;
        size_t o = (size_t)row * N + n2;
        if (outf) outf[o] = s;
        if (outb) outb[o] = f2bf(s);
    }
}

// =================== kernels (5 dispatches) ===================

// D1: gcn-front (0-127) | maxpool (128-2175)
__global__ __launch_bounds__(256, 4) void kD1(const float* __restrict__ feature,
                                              unsigned short* __restrict__ featb,
                                              const float* __restrict__ inp,
                                              const float* __restrict__ W1,
                                              const float* __restrict__ A,
                                              unsigned short* __restrict__ x2b) {
    __shared__ __align__(16) float smem[7760];    // 31 KB
    int b = blockIdx.x;
    if (b < 128) gcn_front_role(b, inp, W1, A, x2b, smem);
    else         maxpool_role(b - 128, feature, featb);
}

// D2: img units (0-511, [N][K] fast path) | xb units (512-639, [K][N] strided)
__global__ __launch_bounds__(256, 4) void kD2(const unsigned short* __restrict__ featb,
                                              const float* __restrict__ W_img,
                                              const float* __restrict__ b_img,
                                              float* __restrict__ img,
                                              const unsigned short* __restrict__ x2b,
                                              const float* __restrict__ W_gc2,
                                              unsigned short* __restrict__ xb) {
    __shared__ __align__(16) float red[4][64][21];   // 21.5 KB
    int b = blockIdx.x;
    if (b < 512) gemm_block<4>(b, featb, W_img, b_img, img, nullptr, 8192, 2048, red);
    else         gemm_block_kn<5>(b - 512, x2b, W_gc2, nullptr, nullptr, xb, 2048, 1024, red);
}

// D3: cls = xb @ W_cls^T + b_cls (512 blocks)
__global__ __launch_bounds__(256, 4) void kD3(const unsigned short* __restrict__ xb,
                                              const float* __restrict__ W_cls,
                                              const float* __restrict__ b_cls,
                                              float* __restrict__ cls) {
    __shared__ __align__(16) float red[4][64][21];
    gemm_block<5>(blockIdx.x, xb, W_cls, b_cls, cls, nullptr, 8192, 2048, red);
}

// D4: G[c2,j] = sum_c cls[c,j] * W_ml[c2, c*1024 + (j>>3)]; 640 blocks (64 o x 10 c2)
__global__ __launch_bounds__(256, 4) void kD4(const float* __restrict__ cls,
                                              const float* __restrict__ W_ml,
                                              float* __restrict__ G) {
    __shared__ __align__(16) float smem[8 * 80 * 16];   // 40 KB
    float (*wml)[80][16] = (float (*)[80][16])smem;
    int idx = blockIdx.x;
    int o0  = (idx & 63) * 16;
    int c2b = (idx >> 6) * 8;
    int j0  = o0 * 8;
    for (int i = threadIdx.x; i < 8 * 80 * 16; i += 256) {
        int ol = i & 15, c = (i >> 4) % 80, c2 = i / 1280;
        wml[c2][c][ol] = W_ml[(size_t)(c2b + c2) * 81920 + c * 1024 + o0 + ol];
    }
    __syncthreads();
    int jl  = threadIdx.x & 127;
    int c2h = (threadIdx.x >> 7) * 4;
    int ol  = jl >> 3;
    float acc[4] = {0.f, 0.f, 0.f, 0.f};
    for (int c = 0; c < 80; c++) {
        float cv = cls[(size_t)c * 8192 + j0 + jl];
        #pragma unroll
        for (int i = 0; i < 4; i++) acc[i] = fmaf(cv, wml[c2h + i][c][ol], acc[i]);
    }
    #pragma unroll
    for (int i = 0; i < 4; i++) G[(size_t)(c2b + c2h + i) * 8192 + j0 + jl] = acc[i];
}

// D5: out[b,c2] = sum_j img[b,j]*G[c2,j] + b_ml[c2]; 160 blocks (16 btile x 10 cg)
__global__ __launch_bounds__(256, 4) void kD5(const float* __restrict__ img,
                                              const float* __restrict__ G,
                                              const float* __restrict__ b_ml,
                                              float* __restrict__ out) {
    __shared__ float sm[4][32];
    int btile = blockIdx.x & 15, cg = blockIdx.x >> 4;
    int kc = threadIdx.x >> 6, lane = threadIdx.x & 63;
    float acc[4][8];
    #pragma unroll
    for (int q = 0; q < 4; q++)
        #pragma unroll
        for (int i = 0; i < 8; i++) acc[q][i] = 0.f;

    #pragma unroll
    for (int step = 0; step < 8; step++) {
        int k = kc * 2048 + step * 256 + lane * 4;
        float4 gv[8];
        #pragma unroll
        for (int i = 0; i < 8; i++) gv[i] = *(const float4*)(G + (size_t)(cg * 8 + i) * 8192 + k);
        #pragma unroll
        for (int q = 0; q < 4; q++) {
            float4 iv = *(const float4*)(img + (size_t)(btile * 4 + q) * 8192 + k);
            #pragma unroll
            for (int i = 0; i < 8; i++) {
                acc[q][i] = fmaf(iv.x, gv[i].x, acc[q][i]);
                acc[q][i] = fmaf(iv.y, gv[i].y, acc[q][i]);
                acc[q][i] = fmaf(iv.z, gv[i].z, acc[q][i]);
                acc[q][i] = fmaf(iv.w, gv[i].w, acc[q][i]);
            }
        }
    }
    #pragma unroll
    for (int q = 0; q < 4; q++)
        #pragma unroll
        for (int i = 0; i < 8; i++) {
            float v = acc[q][i];
            #pragma unroll
            for (int off = 32; off; off >>= 1) v += __shfl_xor(v, off);
            if (lane == 0) sm[kc][q * 8 + i] = v;
        }
    __syncthreads();
    if (threadIdx.x < 32) {
        int i = threadIdx.x & 7;
        float s = b_ml[cg * 8 + i];
        #pragma unroll
        for (int kk = 0; kk < 4; kk++) s += sm[kk][threadIdx.x];
        int q = threadIdx.x >> 3;
        out[(size_t)(btile * 4 + q) * 80 + cg * 8 + i] = s;
    }
}

// ---------------- launch ----------------
extern "C" void kernel_launch(void* const* d_in, const int* in_sizes, int n_in,
                              void* d_out, int out_size, void* d_ws, size_t ws_size,
                              hipStream_t stream) {
    (void)in_sizes; (void)n_in; (void)out_size; (void)ws_size;
    const float* feature = (const float*)d_in[0];
    const float* inp     = (const float*)d_in[1];
    const float* A       = (const float*)d_in[2];
    const float* W_gc1   = (const float*)d_in[3];
    const float* W_gc2   = (const float*)d_in[4];
    const float* W_img   = (const float*)d_in[5];
    const float* b_img   = (const float*)d_in[6];
    const float* W_cls   = (const float*)d_in[7];
    const float* b_cls   = (const float*)d_in[8];
    const float* W_ml    = (const float*)d_in[9];
    const float* b_ml    = (const float*)d_in[10];
    float* out = (float*)d_out;
    char*  ws  = (char*)d_ws;

    unsigned short* featb = (unsigned short*)(ws + OFF_FEATB);
    unsigned short* x2b   = (unsigned short*)(ws + OFF_X2B);
    unsigned short* xb    = (unsigned short*)(ws + OFF_XB);
    float* img  = (float*)(ws + OFF_IMG);
    float* cls  = (float*)(ws + OFF_CLS);
    float* G    = (float*)(ws + OFF_G);

    kD1<<<2176, 256, 0, stream>>>(feature, featb, inp, W_gc1, A, x2b);
    kD2<<<640,  256, 0, stream>>>(featb, W_img, b_img, img, x2b, W_gc2, xb);
    kD3<<<512,  256, 0, stream>>>(xb, W_cls, b_cls, cls);
    kD4<<<640,  256, 0, stream>>>(cls, W_ml, G);
    kD5<<<160,  256, 0, stream>>>(img, G, b_ml, out);
}

// Round 9
// 235.671 us; speedup vs baseline: 1.4951x; 1.1525x over previous
//
#include <hip/hip_runtime.h>
#include <hip/hip_bf16.h>
#include <cstdint>
#include <cstddef>

// ---------------- types / helpers ----------------
typedef float  f32x4  __attribute__((ext_vector_type(4)));
typedef __bf16 bf16x8 __attribute__((ext_vector_type(8)));
typedef unsigned short u16x8 __attribute__((ext_vector_type(8)));

__device__ __forceinline__ unsigned short f2bf(float f) {
    unsigned u = __float_as_uint(f);
    u += 0x7FFFu + ((u >> 16) & 1u);   // round-to-nearest-even
    return (unsigned short)(u >> 16);
}

// ---------------- problem constants ----------------
// B=64, C=80, IN_CH=300, J=8192, S=8, OUT=1024
// feature [64,2048,14,14] (131072 rows of 196), out [64,80]

// ---------------- ws layout (bytes) ----------------
constexpr size_t OFF_FEATB = 0;          // 64*2048 bf16  = 262144
constexpr size_t OFF_X2B   = 262144;     // 80*1024 bf16  = 163840
constexpr size_t OFF_XB    = 425984;     // 80*2048 bf16  = 327680
constexpr size_t OFF_IMG   = 753664;     // 64*8192 f32   = 2097152
constexpr size_t OFF_CLS   = 2850816;    // 80*8192 f32   = 2621440
constexpr size_t OFF_G     = 5472256;    // 80*8192 f32   = 2621440

// =================== D1 roles (256 threads) ===================

// maxpool, MLP-batched: 16 lanes/row, 4 rows/wave, 64 rows/vbid.
// ALL 16 float4 loads issued into registers BEFORE any reduction — this is the
// round-9 fix for the 110 µs latency-bound maxpool (round 8: 2 loads in flight
// at VGPR=44 -> 0.5 TB/s; now 16 in flight -> BW-bound).
__device__ __forceinline__ void maxpool_role(int vbid, const float* __restrict__ feature,
                                             unsigned short* __restrict__ featb) {
    int wave = threadIdx.x >> 6, lane = threadIdx.x & 63;
    int r = lane >> 4, q = lane & 15;
    int rbase = vbid * 64 + wave * 4 + r;           // +16 per it -> 64 rows/block
    const float4* p[4];
    #pragma unroll
    for (int it = 0; it < 4; ++it)
        p[it] = (const float4*)(feature + (size_t)(rbase + it * 16) * 196);
    float4 v[4][4];
    #pragma unroll
    for (int it = 0; it < 4; ++it) {
        v[it][0] = p[it][q];
        v[it][1] = p[it][q + 16];
        v[it][2] = p[it][q + 32];
        v[it][3] = p[it][48];        // tail 192..195, broadcast; max is idempotent
    }
    #pragma unroll
    for (int it = 0; it < 4; ++it) {
        float4 a = v[it][0], b = v[it][1], c = v[it][2], d = v[it][3];
        float m = fmaxf(fmaxf(fmaxf(fmaxf(a.x, a.y), fmaxf(a.z, a.w)),
                              fmaxf(fmaxf(b.x, b.y), fmaxf(b.z, b.w))),
                        fmaxf(fmaxf(fmaxf(c.x, c.y), fmaxf(c.z, c.w)),
                              fmaxf(fmaxf(d.x, d.y), fmaxf(d.z, d.w))));
        #pragma unroll
        for (int off = 1; off < 16; off <<= 1) m = fmaxf(m, __shfl_xor(m, off));
        if (q == 0) featb[rbase + it * 16] = f2bf(m);
    }
}

// GCN front: block owns 8 j-columns (j0 = idx*8). Thread (j = t&7, slot = t>>3)
// computes y0/x1/x2 for c = {slot, slot+32, slot+64(<80)}. W1 column value is
// loaded ONCE per k and reused across the 3 c-accumulators (register reuse).
// 128 blocks x 32 slots -> every (c,j) exactly once. All f32; x2 -> bf16.
__device__ __forceinline__ void gcn_front_role(int idx, const float* __restrict__ inp,
                                               const float* __restrict__ W1,
                                               const float* __restrict__ A,
                                               unsigned short* __restrict__ x2b,
                                               float* smem) {
    float* adjs = smem;            // [80][80] 25600 f
    float* y0s  = smem + 6400;     // [80][8]
    float* x1s  = smem + 7040;     // [80][8]
    float* dinv = smem + 7680;     // [80]
    int t = threadIdx.x;
    int j = t & 7, slot = t >> 3;                 // slot 0..31
    int j0 = idx * 8;
    int c0 = slot, c1 = slot + 32, c2 = slot + 64;
    bool has3 = (slot < 16);                      // wave-uniform

    if (t < 80) {
        const float4* ar = (const float4*)(A + t * 80);
        float4 s4 = {0.f, 0.f, 0.f, 0.f};
        #pragma unroll
        for (int q = 0; q < 20; q++) {
            float4 v = ar[q];
            s4.x += v.x; s4.y += v.y; s4.z += v.z; s4.w += v.w;
        }
        dinv[t] = 1.0f / sqrtf(s4.x + s4.y + s4.z + s4.w);
    }
    __syncthreads();
    for (int i = t; i < 6400; i += 256) {
        int r = i / 80, cc = i % 80;
        adjs[i] = A[cc * 80 + r] * dinv[r] * dinv[cc];
    }

    // y0: 300 serial k, W1 column loads batched 4-deep for MLP
    const float* wcol = W1 + j0 + j;
    const float* i0 = inp + c0 * 300;
    const float* i1 = inp + c1 * 300;
    const float* i2 = inp + c2 * 300;
    float a0 = 0.f, a1 = 0.f, a2 = 0.f;
    for (int k = 0; k < 300; k += 4) {
        float w[4], p0[4], p1[4], p2[4];
        #pragma unroll
        for (int u = 0; u < 4; u++) w[u] = wcol[(size_t)(k + u) * 1024];
        #pragma unroll
        for (int u = 0; u < 4; u++) p0[u] = i0[k + u];
        #pragma unroll
        for (int u = 0; u < 4; u++) p1[u] = i1[k + u];
        if (has3) {
            #pragma unroll
            for (int u = 0; u < 4; u++) p2[u] = i2[k + u];
        }
        #pragma unroll
        for (int u = 0; u < 4; u++) {
            a0 = fmaf(p0[u], w[u], a0);
            a1 = fmaf(p1[u], w[u], a1);
            if (has3) a2 = fmaf(p2[u], w[u], a2);
        }
    }
    __syncthreads();                               // adjs fill complete
    y0s[c0 * 8 + j] = a0;
    y0s[c1 * 8 + j] = a1;
    if (has3) y0s[c2 * 8 + j] = a2;
    __syncthreads();                               // y0s visible

    // x1 = leaky(adj @ y0) for this block's j-slice
    float b0 = 0.f, b1 = 0.f, b2 = 0.f;
    #pragma unroll 4
    for (int e = 0; e < 80; e++) {
        float y = y0s[e * 8 + j];
        b0 = fmaf(adjs[c0 * 80 + e], y, b0);
        b1 = fmaf(adjs[c1 * 80 + e], y, b1);
        if (has3) b2 = fmaf(adjs[c2 * 80 + e], y, b2);
    }
    if (b0 < 0.f) b0 *= 0.2f;
    if (b1 < 0.f) b1 *= 0.2f;
    if (b2 < 0.f) b2 *= 0.2f;
    x1s[c0 * 8 + j] = b0;
    x1s[c1 * 8 + j] = b1;
    if (has3) x1s[c2 * 8 + j] = b2;
    __syncthreads();                               // x1s visible

    // x2 = adj @ x1 -> bf16 global
    float d0 = 0.f, d1 = 0.f, d2 = 0.f;
    #pragma unroll 4
    for (int e = 0; e < 80; e++) {
        float x = x1s[e * 8 + j];
        d0 = fmaf(adjs[c0 * 80 + e], x, d0);
        d1 = fmaf(adjs[c1 * 80 + e], x, d1);
        if (has3) d2 = fmaf(adjs[c2 * 80 + e], x, d2);
    }
    x2b[c0 * 1024 + j0 + j] = f2bf(d0);
    x2b[c1 * 1024 + j0 + j] = f2bf(d1);
    if (has3) x2b[c2 * 1024 + j0 + j] = f2bf(d2);
}

// =================== MFMA GEMMs (256 thr, BN=16, in-block 4-way K-split) ===================
// W in [N][K] row-major (K-contiguous): fast float4 loads.
template <int MF>
__device__ __forceinline__ void gemm_block(int bx, const unsigned short* __restrict__ X,
                                           const float* __restrict__ W,
                                           const float* __restrict__ bias,
                                           float* __restrict__ outf,
                                           unsigned short* __restrict__ outb,
                                           int N, int K, float (*red)[64][21]) {
    int tid = threadIdx.x;
    int ks = tid >> 6, lane = tid & 63;           // wave = k-split
    int n = bx * 16 + (lane & 15);
    int rowa = lane & 15;
    int koff = (lane >> 4) * 8;
    int Kc = K >> 2;
    int k0 = ks * Kc;

    f32x4 acc[MF];
    #pragma unroll
    for (int i = 0; i < MF; i++) acc[i] = (f32x4)(0.f);

    const float* wrow = W + (size_t)n * K;

    #pragma unroll 2
    for (int k = k0; k < k0 + Kc; k += 32) {
        float4 w0 = *(const float4*)(wrow + k + koff);
        float4 w1 = *(const float4*)(wrow + k + koff + 4);
        u16x8 bu;
        bu[0] = f2bf(w0.x); bu[1] = f2bf(w0.y); bu[2] = f2bf(w0.z); bu[3] = f2bf(w0.w);
        bu[4] = f2bf(w1.x); bu[5] = f2bf(w1.y); bu[6] = f2bf(w1.z); bu[7] = f2bf(w1.w);
        bf16x8 bf = __builtin_bit_cast(bf16x8, bu);
        #pragma unroll
        for (int mf = 0; mf < MF; mf++) {
            u16x8 au = *(const u16x8*)(X + (size_t)(mf * 16 + rowa) * K + k + koff);
            acc[mf] = __builtin_amdgcn_mfma_f32_16x16x32_bf16(
                __builtin_bit_cast(bf16x8, au), bf, acc[mf], 0, 0, 0);
        }
    }

    #pragma unroll
    for (int mf = 0; mf < MF; mf++)
        #pragma unroll
        for (int i = 0; i < 4; i++)
            red[ks][lane][mf * 4 + i] = acc[mf][i];
    __syncthreads();

    int lane2 = tid & 63, sg = tid >> 6;
    int n2 = bx * 16 + (lane2 & 15);
    float b = bias ? bias[n2] : 0.f;
    #pragma unroll
    for (int mf = 0; mf < MF; mf++) {
        int slot = mf * 4 + sg;
        float s = red[0][lane2][slot] + red[1][lane2][slot]
                + red[2][lane2][slot] + red[3][lane2][slot] + b;
        int row = mf * 16 + (lane2 >> 4) * 4 + sg;
        size_t o = (size_t)row * N + n2;
        if (outf) outf[o] = s;
        if (outb) outb[o] = f2bf(s);
    }
}

// W in [K][N] row-major (N-contiguous): strided B loads — no transpose needed.
template <int MF>
__device__ __forceinline__ void gemm_block_kn(int bx, const unsigned short* __restrict__ X,
                                              const float* __restrict__ Wkn,
                                              const float* __restrict__ bias,
                                              float* __restrict__ outf,
                                              unsigned short* __restrict__ outb,
                                              int N, int K, float (*red)[64][21]) {
    int tid = threadIdx.x;
    int ks = tid >> 6, lane = tid & 63;
    int n = bx * 16 + (lane & 15);
    int rowa = lane & 15;
    int koff = (lane >> 4) * 8;
    int Kc = K >> 2;
    int k0 = ks * Kc;

    f32x4 acc[MF];
    #pragma unroll
    for (int i = 0; i < MF; i++) acc[i] = (f32x4)(0.f);

    #pragma unroll 2
    for (int k = k0; k < k0 + Kc; k += 32) {
        float w[8];
        #pragma unroll
        for (int i = 0; i < 8; i++) w[i] = Wkn[(size_t)(k + koff + i) * N + n];
        u16x8 bu;
        #pragma unroll
        for (int i = 0; i < 8; i++) bu[i] = f2bf(w[i]);
        bf16x8 bf = __builtin_bit_cast(bf16x8, bu);
        #pragma unroll
        for (int mf = 0; mf < MF; mf++) {
            u16x8 au = *(const u16x8*)(X + (size_t)(mf * 16 + rowa) * K + k + koff);
            acc[mf] = __builtin_amdgcn_mfma_f32_16x16x32_bf16(
                __builtin_bit_cast(bf16x8, au), bf, acc[mf], 0, 0, 0);
        }
    }

    #pragma unroll
    for (int mf = 0; mf < MF; mf++)
        #pragma unroll
        for (int i = 0; i < 4; i++)
            red[ks][lane][mf * 4 + i] = acc[mf][i];
    __syncthreads();

    int lane2 = tid & 63, sg = tid >> 6;
    int n2 = bx * 16 + (lane2 & 15);
    float b = bias ? bias[n2] : 0.f;
    #pragma unroll
    for (int mf = 0; mf < MF; mf++) {
        int slot = mf * 4 + sg;
        float s = red[0][lane2][slot] + red[1][lane2][slot]
                + red[2][lane2][slot] + red[3][lane2][slot] + b;
        int row = mf * 16 + (lane2 >> 4) * 4 + sg;
        size_t o = (size_t)row * N + n2;
        if (outf) outf[o] = s;
        if (outb) outb[o] = f2bf(s);
    }
}

// =================== kernels (5 dispatches) ===================

// D1: gcn-front (0-127) | maxpool (128-2175). launch_bounds(256,2) so the
// batched maxpool loads get VGPR room (round-8: 44 VGPR -> 2 loads in flight).
__global__ __launch_bounds__(256, 2) void kD1(const float* __restrict__ feature,
                                              unsigned short* __restrict__ featb,
                                              const float* __restrict__ inp,
                                              const float* __restrict__ W1,
                                              const float* __restrict__ A,
                                              unsigned short* __restrict__ x2b) {
    __shared__ __align__(16) float smem[7760];    // 31 KB
    int b = blockIdx.x;
    if (b < 128) gcn_front_role(b, inp, W1, A, x2b, smem);
    else         maxpool_role(b - 128, feature, featb);
}

// D2: img units (0-511, [N][K] fast path) | xb units (512-639, [K][N] strided)
__global__ __launch_bounds__(256, 4) void kD2(const unsigned short* __restrict__ featb,
                                              const float* __restrict__ W_img,
                                              const float* __restrict__ b_img,
                                              float* __restrict__ img,
                                              const unsigned short* __restrict__ x2b,
                                              const float* __restrict__ W_gc2,
                                              unsigned short* __restrict__ xb) {
    __shared__ __align__(16) float red[4][64][21];   // 21.5 KB
    int b = blockIdx.x;
    if (b < 512) gemm_block<4>(b, featb, W_img, b_img, img, nullptr, 8192, 2048, red);
    else         gemm_block_kn<5>(b - 512, x2b, W_gc2, nullptr, nullptr, xb, 2048, 1024, red);
}

// D3: cls = xb @ W_cls^T + b_cls (512 blocks)
__global__ __launch_bounds__(256, 4) void kD3(const unsigned short* __restrict__ xb,
                                              const float* __restrict__ W_cls,
                                              const float* __restrict__ b_cls,
                                              float* __restrict__ cls) {
    __shared__ __align__(16) float red[4][64][21];
    gemm_block<5>(blockIdx.x, xb, W_cls, b_cls, cls, nullptr, 8192, 2048, red);
}

// D4: G[c2,j] = sum_c cls[c,j] * W_ml[c2, c*1024 + (j>>3)]; 640 blocks (64 o x 10 c2)
__global__ __launch_bounds__(256, 4) void kD4(const float* __restrict__ cls,
                                              const float* __restrict__ W_ml,
                                              float* __restrict__ G) {
    __shared__ __align__(16) float smem[8 * 80 * 16];   // 40 KB
    float (*wml)[80][16] = (float (*)[80][16])smem;
    int idx = blockIdx.x;
    int o0  = (idx & 63) * 16;
    int c2b = (idx >> 6) * 8;
    int j0  = o0 * 8;
    for (int i = threadIdx.x; i < 8 * 80 * 16; i += 256) {
        int ol = i & 15, c = (i >> 4) % 80, c2 = i / 1280;
        wml[c2][c][ol] = W_ml[(size_t)(c2b + c2) * 81920 + c * 1024 + o0 + ol];
    }
    __syncthreads();
    int jl  = threadIdx.x & 127;
    int c2h = (threadIdx.x >> 7) * 4;
    int ol  = jl >> 3;
    float acc[4] = {0.f, 0.f, 0.f, 0.f};
    for (int c = 0; c < 80; c++) {
        float cv = cls[(size_t)c * 8192 + j0 + jl];
        #pragma unroll
        for (int i = 0; i < 4; i++) acc[i] = fmaf(cv, wml[c2h + i][c][ol], acc[i]);
    }
    #pragma unroll
    for (int i = 0; i < 4; i++) G[(size_t)(c2b + c2h + i) * 8192 + j0 + jl] = acc[i];
}

// D5: out[b,c2] = sum_j img[b,j]*G[c2,j] + b_ml[c2]; 160 blocks (16 btile x 10 cg)
__global__ __launch_bounds__(256, 4) void kD5(const float* __restrict__ img,
                                              const float* __restrict__ G,
                                              const float* __restrict__ b_ml,
                                              float* __restrict__ out) {
    __shared__ float sm[4][32];
    int btile = blockIdx.x & 15, cg = blockIdx.x >> 4;
    int kc = threadIdx.x >> 6, lane = threadIdx.x & 63;
    float acc[4][8];
    #pragma unroll
    for (int q = 0; q < 4; q++)
        #pragma unroll
        for (int i = 0; i < 8; i++) acc[q][i] = 0.f;

    #pragma unroll
    for (int step = 0; step < 8; step++) {
        int k = kc * 2048 + step * 256 + lane * 4;
        float4 gv[8];
        #pragma unroll
        for (int i = 0; i < 8; i++) gv[i] = *(const float4*)(G + (size_t)(cg * 8 + i) * 8192 + k);
        #pragma unroll
        for (int q = 0; q < 4; q++) {
            float4 iv = *(const float4*)(img + (size_t)(btile * 4 + q) * 8192 + k);
            #pragma unroll
            for (int i = 0; i < 8; i++) {
                acc[q][i] = fmaf(iv.x, gv[i].x, acc[q][i]);
                acc[q][i] = fmaf(iv.y, gv[i].y, acc[q][i]);
                acc[q][i] = fmaf(iv.z, gv[i].z, acc[q][i]);
                acc[q][i] = fmaf(iv.w, gv[i].w, acc[q][i]);
            }
        }
    }
    #pragma unroll
    for (int q = 0; q < 4; q++)
        #pragma unroll
        for (int i = 0; i < 8; i++) {
            float v = acc[q][i];
            #pragma unroll
            for (int off = 32; off; off >>= 1) v += __shfl_xor(v, off);
            if (lane == 0) sm[kc][q * 8 + i] = v;
        }
    __syncthreads();
    if (threadIdx.x < 32) {
        int i = threadIdx.x & 7;
        float s = b_ml[cg * 8 + i];
        #pragma unroll
        for (int kk = 0; kk < 4; kk++) s += sm[kk][threadIdx.x];
        int q = threadIdx.x >> 3;
        out[(size_t)(btile * 4 + q) * 80 + cg * 8 + i] = s;
    }
}

// ---------------- launch ----------------
extern "C" void kernel_launch(void* const* d_in, const int* in_sizes, int n_in,
                              void* d_out, int out_size, void* d_ws, size_t ws_size,
                              hipStream_t stream) {
    (void)in_sizes; (void)n_in; (void)out_size; (void)ws_size;
    const float* feature = (const float*)d_in[0];
    const float* inp     = (const float*)d_in[1];
    const float* A       = (const float*)d_in[2];
    const float* W_gc1   = (const float*)d_in[3];
    const float* W_gc2   = (const float*)d_in[4];
    const float* W_img   = (const float*)d_in[5];
    const float* b_img   = (const float*)d_in[6];
    const float* W_cls   = (const float*)d_in[7];
    const float* b_cls   = (const float*)d_in[8];
    const float* W_ml    = (const float*)d_in[9];
    const float* b_ml    = (const float*)d_in[10];
    float* out = (float*)d_out;
    char*  ws  = (char*)d_ws;

    unsigned short* featb = (unsigned short*)(ws + OFF_FEATB);
    unsigned short* x2b   = (unsigned short*)(ws + OFF_X2B);
    unsigned short* xb    = (unsigned short*)(ws + OFF_XB);
    float* img  = (float*)(ws + OFF_IMG);
    float* cls  = (float*)(ws + OFF_CLS);
    float* G    = (float*)(ws + OFF_G);

    kD1<<<2176, 256, 0, stream>>>(feature, featb, inp, W_gc1, A, x2b);
    kD2<<<640,  256, 0, stream>>>(featb, W_img, b_img, img, x2b, W_gc2, xb);
    kD3<<<512,  256, 0, stream>>>(xb, W_cls, b_cls, cls);
    kD4<<<640,  256, 0, stream>>>(cls, W_ml, G);
    kD5<<<160,  256, 0, stream>>>(img, G, b_ml, out);
}

// Round 10
// 149.843 us; speedup vs baseline: 2.3515x; 1.5728x over previous
//
#include <hip/hip_runtime.h>
#include <hip/hip_bf16.h>
#include <cstdint>
#include <cstddef>

// ---------------- types / helpers ----------------
typedef float  f32x4  __attribute__((ext_vector_type(4)));
typedef __bf16 bf16x8 __attribute__((ext_vector_type(8)));
typedef unsigned short u16x8 __attribute__((ext_vector_type(8)));

__device__ __forceinline__ unsigned short f2bf(float f) {
    unsigned u = __float_as_uint(f);
    u += 0x7FFFu + ((u >> 16) & 1u);   // round-to-nearest-even
    return (unsigned short)(u >> 16);
}

// ---------------- problem constants ----------------
// B=64, C=80, IN_CH=300, J=8192, S=8, OUT=1024
// feature [64,2048,14,14] (131072 rows of 196), out [64,80]

// ---------------- ws layout (bytes) ----------------
constexpr size_t OFF_FEATB = 0;          // 64*2048 bf16  = 262144
constexpr size_t OFF_X2B   = 262144;     // 80*1024 bf16  = 163840
constexpr size_t OFF_XB    = 425984;     // 80*2048 bf16  = 327680
constexpr size_t OFF_IMG   = 753664;     // 64*8192 f32   = 2097152
constexpr size_t OFF_CLS   = 2850816;    // 80*8192 f32   = 2621440
constexpr size_t OFF_G     = 5472256;    // 80*8192 f32   = 2621440

// =================== D1 roles (256 threads) ===================

// maxpool, MLP-batched: 16 lanes/row, 4 rows/wave, 64 rows/vbid.
__device__ __forceinline__ void maxpool_role(int vbid, const float* __restrict__ feature,
                                             unsigned short* __restrict__ featb) {
    int wave = threadIdx.x >> 6, lane = threadIdx.x & 63;
    int r = lane >> 4, q = lane & 15;
    int rbase = vbid * 64 + wave * 4 + r;           // +16 per it -> 64 rows/block
    const float4* p[4];
    #pragma unroll
    for (int it = 0; it < 4; ++it)
        p[it] = (const float4*)(feature + (size_t)(rbase + it * 16) * 196);
    float4 v[4][4];
    #pragma unroll
    for (int it = 0; it < 4; ++it) {
        v[it][0] = p[it][q];
        v[it][1] = p[it][q + 16];
        v[it][2] = p[it][q + 32];
        v[it][3] = p[it][48];        // tail 192..195, broadcast; max is idempotent
    }
    #pragma unroll
    for (int it = 0; it < 4; ++it) {
        float4 a = v[it][0], b = v[it][1], c = v[it][2], d = v[it][3];
        float m = fmaxf(fmaxf(fmaxf(fmaxf(a.x, a.y), fmaxf(a.z, a.w)),
                              fmaxf(fmaxf(b.x, b.y), fmaxf(b.z, b.w))),
                        fmaxf(fmaxf(fmaxf(c.x, c.y), fmaxf(c.z, c.w)),
                              fmaxf(fmaxf(d.x, d.y), fmaxf(d.z, d.w))));
        #pragma unroll
        for (int off = 1; off < 16; off <<= 1) m = fmaxf(m, __shfl_xor(m, off));
        if (q == 0) featb[rbase + it * 16] = f2bf(m);
    }
}

// GCN front: block owns 8 j-columns (j0 = idx*8). Thread (j = t&7, slot = t>>3)
// computes y0/x1/x2 for c = {slot, slot+32, slot+64(<80)}. W1 column value is
// loaded ONCE per k and reused across the 3 c-accumulators (register reuse).
__device__ __forceinline__ void gcn_front_role(int idx, const float* __restrict__ inp,
                                               const float* __restrict__ W1,
                                               const float* __restrict__ A,
                                               unsigned short* __restrict__ x2b,
                                               float* smem) {
    float* adjs = smem;            // [80][80] 25600 f
    float* y0s  = smem + 6400;     // [80][8]
    float* x1s  = smem + 7040;     // [80][8]
    float* dinv = smem + 7680;     // [80]
    int t = threadIdx.x;
    int j = t & 7, slot = t >> 3;                 // slot 0..31
    int j0 = idx * 8;
    int c0 = slot, c1 = slot + 32, c2 = slot + 64;
    bool has3 = (slot < 16);                      // wave-uniform

    if (t < 80) {
        const float4* ar = (const float4*)(A + t * 80);
        float4 s4 = {0.f, 0.f, 0.f, 0.f};
        #pragma unroll
        for (int q = 0; q < 20; q++) {
            float4 v = ar[q];
            s4.x += v.x; s4.y += v.y; s4.z += v.z; s4.w += v.w;
        }
        dinv[t] = 1.0f / sqrtf(s4.x + s4.y + s4.z + s4.w);
    }
    __syncthreads();
    for (int i = t; i < 6400; i += 256) {
        int r = i / 80, cc = i % 80;
        adjs[i] = A[cc * 80 + r] * dinv[r] * dinv[cc];
    }

    // y0: 300 serial k, W1 column loads batched 4-deep for MLP
    const float* wcol = W1 + j0 + j;
    const float* i0 = inp + c0 * 300;
    const float* i1 = inp + c1 * 300;
    const float* i2 = inp + c2 * 300;
    float a0 = 0.f, a1 = 0.f, a2 = 0.f;
    for (int k = 0; k < 300; k += 4) {
        float w[4], p0[4], p1[4], p2[4];
        #pragma unroll
        for (int u = 0; u < 4; u++) w[u] = wcol[(size_t)(k + u) * 1024];
        #pragma unroll
        for (int u = 0; u < 4; u++) p0[u] = i0[k + u];
        #pragma unroll
        for (int u = 0; u < 4; u++) p1[u] = i1[k + u];
        if (has3) {
            #pragma unroll
            for (int u = 0; u < 4; u++) p2[u] = i2[k + u];
        }
        #pragma unroll
        for (int u = 0; u < 4; u++) {
            a0 = fmaf(p0[u], w[u], a0);
            a1 = fmaf(p1[u], w[u], a1);
            if (has3) a2 = fmaf(p2[u], w[u], a2);
        }
    }
    __syncthreads();                               // adjs fill complete
    y0s[c0 * 8 + j] = a0;
    y0s[c1 * 8 + j] = a1;
    if (has3) y0s[c2 * 8 + j] = a2;
    __syncthreads();                               // y0s visible

    // x1 = leaky(adj @ y0) for this block's j-slice
    float b0 = 0.f, b1 = 0.f, b2 = 0.f;
    #pragma unroll 4
    for (int e = 0; e < 80; e++) {
        float y = y0s[e * 8 + j];
        b0 = fmaf(adjs[c0 * 80 + e], y, b0);
        b1 = fmaf(adjs[c1 * 80 + e], y, b1);
        if (has3) b2 = fmaf(adjs[c2 * 80 + e], y, b2);
    }
    if (b0 < 0.f) b0 *= 0.2f;
    if (b1 < 0.f) b1 *= 0.2f;
    if (b2 < 0.f) b2 *= 0.2f;
    x1s[c0 * 8 + j] = b0;
    x1s[c1 * 8 + j] = b1;
    if (has3) x1s[c2 * 8 + j] = b2;
    __syncthreads();                               // x1s visible

    // x2 = adj @ x1 -> bf16 global
    float d0 = 0.f, d1 = 0.f, d2 = 0.f;
    #pragma unroll 4
    for (int e = 0; e < 80; e++) {
        float x = x1s[e * 8 + j];
        d0 = fmaf(adjs[c0 * 80 + e], x, d0);
        d1 = fmaf(adjs[c1 * 80 + e], x, d1);
        if (has3) d2 = fmaf(adjs[c2 * 80 + e], x, d2);
    }
    x2b[c0 * 1024 + j0 + j] = f2bf(d0);
    x2b[c1 * 1024 + j0 + j] = f2bf(d1);
    if (has3) x2b[c2 * 1024 + j0 + j] = f2bf(d2);
}

// =================== MFMA GEMMs (256 thr, BN=16, in-block 4-way K-split) ===================
// W in [N][K] row-major (K-contiguous): fast float4 loads.
template <int MF>
__device__ __forceinline__ void gemm_block(int bx, const unsigned short* __restrict__ X,
                                           const float* __restrict__ W,
                                           const float* __restrict__ bias,
                                           float* __restrict__ outf,
                                           unsigned short* __restrict__ outb,
                                           int N, int K, float (*red)[64][21]) {
    int tid = threadIdx.x;
    int ks = tid >> 6, lane = tid & 63;           // wave = k-split
    int n = bx * 16 + (lane & 15);
    int rowa = lane & 15;
    int koff = (lane >> 4) * 8;
    int Kc = K >> 2;
    int k0 = ks * Kc;

    f32x4 acc[MF];
    #pragma unroll
    for (int i = 0; i < MF; i++) acc[i] = (f32x4)(0.f);

    const float* wrow = W + (size_t)n * K;

    #pragma unroll 2
    for (int k = k0; k < k0 + Kc; k += 32) {
        float4 w0 = *(const float4*)(wrow + k + koff);
        float4 w1 = *(const float4*)(wrow + k + koff + 4);
        u16x8 bu;
        bu[0] = f2bf(w0.x); bu[1] = f2bf(w0.y); bu[2] = f2bf(w0.z); bu[3] = f2bf(w0.w);
        bu[4] = f2bf(w1.x); bu[5] = f2bf(w1.y); bu[6] = f2bf(w1.z); bu[7] = f2bf(w1.w);
        bf16x8 bf = __builtin_bit_cast(bf16x8, bu);
        #pragma unroll
        for (int mf = 0; mf < MF; mf++) {
            u16x8 au = *(const u16x8*)(X + (size_t)(mf * 16 + rowa) * K + k + koff);
            acc[mf] = __builtin_amdgcn_mfma_f32_16x16x32_bf16(
                __builtin_bit_cast(bf16x8, au), bf, acc[mf], 0, 0, 0);
        }
    }

    #pragma unroll
    for (int mf = 0; mf < MF; mf++)
        #pragma unroll
        for (int i = 0; i < 4; i++)
            red[ks][lane][mf * 4 + i] = acc[mf][i];
    __syncthreads();

    int lane2 = tid & 63, sg = tid >> 6;
    int n2 = bx * 16 + (lane2 & 15);
    float b = bias ? bias[n2] : 0.f;
    #pragma unroll
    for (int mf = 0; mf < MF; mf++) {
        int slot = mf * 4 + sg;
        float s = red[0][lane2][slot] + red[1][lane2][slot]
                + red[2][lane2][slot] + red[3][lane2][slot] + b;
        int row = mf * 16 + (lane2 >> 4) * 4 + sg;
        size_t o = (size_t)row * N + n2;
        if (outf) outf[o] = s;
        if (outb) outb[o] = f2bf(s);
    }
}

// W in [K][N] row-major (N-contiguous): strided B loads — no transpose needed.
template <int MF>
__device__ __forceinline__ void gemm_block_kn(int bx, const unsigned short* __restrict__ X,
                                              const float* __restrict__ Wkn,
                                              const float* __restrict__ bias,
                                              float* __restrict__ outf,
                                              unsigned short* __restrict__ outb,
                                              int N, int K, float (*red)[64][21]) {
    int tid = threadIdx.x;
    int ks = tid >> 6, lane = tid & 63;
    int n = bx * 16 + (lane & 15);
    int rowa = lane & 15;
    int koff = (lane >> 4) * 8;
    int Kc = K >> 2;
    int k0 = ks * Kc;

    f32x4 acc[MF];
    #pragma unroll
    for (int i = 0; i < MF; i++) acc[i] = (f32x4)(0.f);

    #pragma unroll 2
    for (int k = k0; k < k0 + Kc; k += 32) {
        float w[8];
        #pragma unroll
        for (int i = 0; i < 8; i++) w[i] = Wkn[(size_t)(k + koff + i) * N + n];
        u16x8 bu;
        #pragma unroll
        for (int i = 0; i < 8; i++) bu[i] = f2bf(w[i]);
        bf16x8 bf = __builtin_bit_cast(bf16x8, bu);
        #pragma unroll
        for (int mf = 0; mf < MF; mf++) {
            u16x8 au = *(const u16x8*)(X + (size_t)(mf * 16 + rowa) * K + k + koff);
            acc[mf] = __builtin_amdgcn_mfma_f32_16x16x32_bf16(
                __builtin_bit_cast(bf16x8, au), bf, acc[mf], 0, 0, 0);
        }
    }

    #pragma unroll
    for (int mf = 0; mf < MF; mf++)
        #pragma unroll
        for (int i = 0; i < 4; i++)
            red[ks][lane][mf * 4 + i] = acc[mf][i];
    __syncthreads();

    int lane2 = tid & 63, sg = tid >> 6;
    int n2 = bx * 16 + (lane2 & 15);
    float b = bias ? bias[n2] : 0.f;
    #pragma unroll
    for (int mf = 0; mf < MF; mf++) {
        int slot = mf * 4 + sg;
        float s = red[0][lane2][slot] + red[1][lane2][slot]
                + red[2][lane2][slot] + red[3][lane2][slot] + b;
        int row = mf * 16 + (lane2 >> 4) * 4 + sg;
        size_t o = (size_t)row * N + n2;
        if (outf) outf[o] = s;
        if (outb) outb[o] = f2bf(s);
    }
}

// =================== kernels (5 dispatches) ===================

// D1: gcn-front (0-127) | maxpool (128-2175)
__global__ __launch_bounds__(256, 2) void kD1(const float* __restrict__ feature,
                                              unsigned short* __restrict__ featb,
                                              const float* __restrict__ inp,
                                              const float* __restrict__ W1,
                                              const float* __restrict__ A,
                                              unsigned short* __restrict__ x2b) {
    __shared__ __align__(16) float smem[7760];    // 31 KB
    int b = blockIdx.x;
    if (b < 128) gcn_front_role(b, inp, W1, A, x2b, smem);
    else         maxpool_role(b - 128, feature, featb);
}

// D2: img units (0-511, [N][K] fast path) | xb units (512-639, [K][N] strided)
__global__ __launch_bounds__(256, 4) void kD2(const unsigned short* __restrict__ featb,
                                              const float* __restrict__ W_img,
                                              const float* __restrict__ b_img,
                                              float* __restrict__ img,
                                              const unsigned short* __restrict__ x2b,
                                              const float* __restrict__ W_gc2,
                                              unsigned short* __restrict__ xb) {
    __shared__ __align__(16) float red[4][64][21];   // 21.5 KB
    int b = blockIdx.x;
    if (b < 512) gemm_block<4>(b, featb, W_img, b_img, img, nullptr, 8192, 2048, red);
    else         gemm_block_kn<5>(b - 512, x2b, W_gc2, nullptr, nullptr, xb, 2048, 1024, red);
}

// D3: cls = xb @ W_cls^T + b_cls (512 blocks)
__global__ __launch_bounds__(256, 4) void kD3(const unsigned short* __restrict__ xb,
                                              const float* __restrict__ W_cls,
                                              const float* __restrict__ b_cls,
                                              float* __restrict__ cls) {
    __shared__ __align__(16) float red[4][64][21];
    gemm_block<5>(blockIdx.x, xb, W_cls, b_cls, cls, nullptr, 8192, 2048, red);
}

// D4: G[c2,j] = sum_c cls[c,j] * W_ml[c2, c*1024 + (j>>3)]; 640 blocks (64 o x 10 c2)
__global__ __launch_bounds__(256, 4) void kD4(const float* __restrict__ cls,
                                              const float* __restrict__ W_ml,
                                              float* __restrict__ G) {
    __shared__ __align__(16) float smem[8 * 80 * 16];   // 40 KB
    float (*wml)[80][16] = (float (*)[80][16])smem;
    int idx = blockIdx.x;
    int o0  = (idx & 63) * 16;
    int c2b = (idx >> 6) * 8;
    int j0  = o0 * 8;
    for (int i = threadIdx.x; i < 8 * 80 * 16; i += 256) {
        int ol = i & 15, c = (i >> 4) % 80, c2 = i / 1280;
        wml[c2][c][ol] = W_ml[(size_t)(c2b + c2) * 81920 + c * 1024 + o0 + ol];
    }
    __syncthreads();
    int jl  = threadIdx.x & 127;
    int c2h = (threadIdx.x >> 7) * 4;
    int ol  = jl >> 3;
    float acc[4] = {0.f, 0.f, 0.f, 0.f};
    for (int c = 0; c < 80; c++) {
        float cv = cls[(size_t)c * 8192 + j0 + jl];
        #pragma unroll
        for (int i = 0; i < 4; i++) acc[i] = fmaf(cv, wml[c2h + i][c][ol], acc[i]);
    }
    #pragma unroll
    for (int i = 0; i < 4; i++) G[(size_t)(c2b + c2h + i) * 8192 + j0 + jl] = acc[i];
}

// D5 (round-10 rewrite): out[b,c2] = sum_j img[b,j]*G[c2,j] + b_ml[c2].
// 640 blocks = b(64) x cg(10); 4 waves = k-quarters; acc[8] scalars per thread
// (round 9: acc[4][8]+gv[8] at VGPR cap 64 -> 42 MB scratch spill = 99 us).
__global__ __launch_bounds__(256, 2) void kD5(const float* __restrict__ img,
                                              const float* __restrict__ G,
                                              const float* __restrict__ b_ml,
                                              float* __restrict__ out) {
    __shared__ float sm[4][8];
    int b = blockIdx.x / 10, cg = blockIdx.x % 10;
    int kc = threadIdx.x >> 6, lane = threadIdx.x & 63;
    const float* ib = img + (size_t)b * 8192 + kc * 2048;
    const float* gb = G + (size_t)(cg * 8) * 8192 + kc * 2048;
    float acc[8] = {0.f, 0.f, 0.f, 0.f, 0.f, 0.f, 0.f, 0.f};
    #pragma unroll
    for (int step = 0; step < 8; step++) {
        int k = step * 256 + lane * 4;
        float4 iv = *(const float4*)(ib + k);
        float4 gv[8];
        #pragma unroll
        for (int i = 0; i < 8; i++) gv[i] = *(const float4*)(gb + (size_t)i * 8192 + k);
        #pragma unroll
        for (int i = 0; i < 8; i++) {
            acc[i] = fmaf(iv.x, gv[i].x, acc[i]);
            acc[i] = fmaf(iv.y, gv[i].y, acc[i]);
            acc[i] = fmaf(iv.z, gv[i].z, acc[i]);
            acc[i] = fmaf(iv.w, gv[i].w, acc[i]);
        }
    }
    #pragma unroll
    for (int i = 0; i < 8; i++) {
        float v = acc[i];
        #pragma unroll
        for (int off = 32; off; off >>= 1) v += __shfl_xor(v, off);
        if (lane == 0) sm[kc][i] = v;
    }
    __syncthreads();
    if (threadIdx.x < 8) {
        int i = threadIdx.x;
        float s = b_ml[cg * 8 + i] + sm[0][i] + sm[1][i] + sm[2][i] + sm[3][i];
        out[(size_t)b * 80 + cg * 8 + i] = s;
    }
}

// ---------------- launch ----------------
extern "C" void kernel_launch(void* const* d_in, const int* in_sizes, int n_in,
                              void* d_out, int out_size, void* d_ws, size_t ws_size,
                              hipStream_t stream) {
    (void)in_sizes; (void)n_in; (void)out_size; (void)ws_size;
    const float* feature = (const float*)d_in[0];
    const float* inp     = (const float*)d_in[1];
    const float* A       = (const float*)d_in[2];
    const float* W_gc1   = (const float*)d_in[3];
    const float* W_gc2   = (const float*)d_in[4];
    const float* W_img   = (const float*)d_in[5];
    const float* b_img   = (const float*)d_in[6];
    const float* W_cls   = (const float*)d_in[7];
    const float* b_cls   = (const float*)d_in[8];
    const float* W_ml    = (const float*)d_in[9];
    const float* b_ml    = (const float*)d_in[10];
    float* out = (float*)d_out;
    char*  ws  = (char*)d_ws;

    unsigned short* featb = (unsigned short*)(ws + OFF_FEATB);
    unsigned short* x2b   = (unsigned short*)(ws + OFF_X2B);
    unsigned short* xb    = (unsigned short*)(ws + OFF_XB);
    float* img  = (float*)(ws + OFF_IMG);
    float* cls  = (float*)(ws + OFF_CLS);
    float* G    = (float*)(ws + OFF_G);

    kD1<<<2176, 256, 0, stream>>>(feature, featb, inp, W_gc1, A, x2b);
    kD2<<<640,  256, 0, stream>>>(featb, W_img, b_img, img, x2b, W_gc2, xb);
    kD3<<<512,  256, 0, stream>>>(xb, W_cls, b_cls, cls);
    kD4<<<640,  256, 0, stream>>>(cls, W_ml, G);
    kD5<<<640,  256, 0, stream>>>(img, G, b_ml, out);
}